// Round 11
// baseline (103.444 us; speedup 1.0000x reference)
//
#include <hip/hip_runtime.h>
#include <hip/hip_fp16.h>
#include <hip/hip_bf16.h>

// Problem constants (fixed by reference setup_inputs)
#define B_    4
#define C_    128
#define H_    64
#define W_    64
#define CO_   128
#define K_    9
#define DG_   2
#define HW_   4096
#define CK_   1152
#define NKT_  36        // CK_/32
#define NQP_  288       // CK_/4 channel-quad "qpairs"
#define XSTR_ 68        // LDS plane row stride in h4v elements (8B): bank-rotating

typedef __attribute__((ext_vector_type(8))) short    short8;
typedef __attribute__((ext_vector_type(4))) float    floatx4;
typedef __attribute__((ext_vector_type(2))) _Float16 h2v;
typedef __attribute__((ext_vector_type(4))) _Float16 h4v;    // 8B, one pixel x 4 channels

__device__ __forceinline__ h2v pkrtz(float a, float b) {
    return __builtin_bit_cast(h2v, __builtin_amdgcn_cvt_pkrtz(a, b));  // v_cvt_pkrtz_f16_f32
}

// Static staging buffers, fully rewritten every launch.
// K-dimension reordered k-major: ck' = k*128 + c (A and B agree; GEMM is
// order-invariant). A in MFMA-fragment order: [kt][mt(co16)][lane][8k'].
__device__ __align__(16) unsigned short g_wA[NKT_ * 8 * 64 * 8];
// col 64-pixel-tile-blocked, quad-packed: [b][pt64][qp(288)][pl64] uint2,
// qp = k*32 + c/4; element = {bf16x2(ck'=4q,4q+1), bf16x2(ck'=4q+2,4q+3)}.
__device__ __align__(16) uint2          g_colq[(size_t)B_ * 64 * NQP_ * 64];
__device__ __align__(16) int4           g_desc[B_ * DG_ * K_ * HW_];   // {padded base, h2(w00,w01), h2(w10,w11), 0}

__device__ __forceinline__ unsigned short f32_to_bf16(float f) {
    unsigned int u = __float_as_uint(f);
    u += 0x7FFFu + ((u >> 16) & 1u);           // round-to-nearest-even
    return (unsigned short)(u >> 16);
}
__device__ __forceinline__ unsigned int pack_bf16x2_hw(float a, float b) {
    union { __hip_bfloat162 h; unsigned int u; } cvt;
    cvt.h = __float22bfloat162_rn(make_float2(a, b));  // v_cvt_pk_bf16_f32
    return cvt.u;
}

// ---- Kernel 1: weight -> bf16 A-fragment layout (k-major) + descriptors ----
__global__ __launch_bounds__(256) void prep_kernel(
    const float* __restrict__ w,
    const float* __restrict__ offset,
    const float* __restrict__ mask)
{
    const int bid = blockIdx.x;
    if (bid < 576) {
        // weights: 147456 elements into fragment order, k-major ck'
        const int lin  = bid * 256 + threadIdx.x;
        const int j    = lin & 7;
        const int lane = (lin >> 3) & 63;
        const int mtkt = lin >> 9;             // kt*8 + mt
        const int mt   = mtkt & 7;
        const int kt   = mtkt >> 3;
        const int co   = mt * 16 + (lane & 15);
        const int kp   = kt * 32 + (lane >> 4) * 8 + j;   // ck' = k*128 + c
        const int c    = kp & 127;
        const int k    = kp >> 7;
        g_wA[lin] = f32_to_bf16(w[co * CK_ + c * 9 + k]);
    } else {
        // descriptors: 294912 = 72 bgk * 4096 pix
        const int lin = (bid - 576) * 256 + threadIdx.x;
        const int pix = lin & (HW_ - 1);
        const int bgk = lin >> 12;             // (b*2+g)*9 + k
        const int k   = bgk % 9;
        const int bg  = bgk / 9;
        const int ho = pix >> 6;
        const int wo = pix & 63;
        const int ky = k / 3;
        const int kx = k - 3 * ky;

        const float py = offset[(size_t)(bg * 18 + 2 * k)     * HW_ + pix] + (float)(ho - 1 + ky);
        const float px = offset[(size_t)(bg * 18 + 2 * k + 1) * HW_ + pix] + (float)(wo - 1 + kx);
        const float m  = mask  [(size_t)(bg * 9 + k)          * HW_ + pix];

        const float y0f = floorf(py);
        const float x0f = floorf(px);
        const float ly = py - y0f;
        const float lx = px - x0f;
        const int y0 = (int)y0f;
        const int x0 = (int)x0f;

        // clamped 2x2 load window + folded edge weights
        const bool yin = (y0 >= 0) & (y0 <= H_ - 2);
        const float er0 = yin ? (1.0f - ly) : ((y0 == -1)     ? ly          : 0.0f);
        const float er1 = yin ? ly          : ((y0 == H_ - 1) ? (1.0f - ly) : 0.0f);
        const bool xin = (x0 >= 0) & (x0 <= W_ - 2);
        const float ec0 = xin ? (1.0f - lx) : ((x0 == -1)     ? lx          : 0.0f);
        const float ec1 = xin ? lx          : ((x0 == W_ - 1) ? (1.0f - lx) : 0.0f);
        const int yc = min(max(y0, 0), H_ - 2);
        const int xc = min(max(x0, 0), W_ - 2);

        const __half2 wlo = __floats2half2_rn(m * er0 * ec0, m * er0 * ec1);
        const __half2 whi = __floats2half2_rn(m * er1 * ec0, m * er1 * ec1);
        union { __half2 h; int i; } ulo, uhi;
        ulo.h = wlo; uhi.h = whi;
        int4 d;
        d.x = yc * XSTR_ + xc;                 // padded-plane ELEMENT base
        d.y = ulo.i;
        d.z = uhi.i;
        d.w = 0;
        g_desc[lin] = d;
    }
}

// ---- Kernel 2 (hot): col from 4-channel-interleaved fp16 LDS planes. ----
// Block = (b, channel-quad, pixel-quarter): 512 blocks x 1024 thr (2/CU).
// Tap-row read = ds_read2_b64; bilinear via v_fma_mix_f32 (f16 srcs, f32 acc);
// per-k one uint2 store (512B/wave, contiguous).
__global__ __launch_bounds__(1024) void col_kernel(const float* __restrict__ x)
{
    const int bid = blockIdx.x;            // 512 = 4b * 32cq * 4qu
    const int b   = bid >> 7;
    const int rem = bid & 127;
    const int cq  = rem >> 2;              // channel quad 0..31
    const int qu  = rem & 3;
    const int c0  = cq * 4;
    const int g   = cq >> 4;               // deform group
    const int t   = threadIdx.x;

    __shared__ h4v s_x4[64 * XSTR_];       // 34816 B

    {   // stage 4 planes interleaved: thread t -> pixels 4t..4t+3
        const int p0  = t * 4;
        const int row = p0 >> 6;
        const int col = p0 & 63;
        const float* __restrict__ src = x + ((size_t)(b * C_ + c0) << 12) + p0;
        const float4 f0 = *(const float4*)(src);
        const float4 f1 = *(const float4*)(src + HW_);
        const float4 f2 = *(const float4*)(src + 2 * HW_);
        const float4 f3 = *(const float4*)(src + 3 * HW_);
        h4v* dst = s_x4 + row * XSTR_ + col;
        dst[0] = __builtin_shufflevector(pkrtz(f0.x, f1.x), pkrtz(f2.x, f3.x), 0, 1, 2, 3);
        dst[1] = __builtin_shufflevector(pkrtz(f0.y, f1.y), pkrtz(f2.y, f3.y), 0, 1, 2, 3);
        dst[2] = __builtin_shufflevector(pkrtz(f0.z, f1.z), pkrtz(f2.z, f3.z), 0, 1, 2, 3);
        dst[3] = __builtin_shufflevector(pkrtz(f0.w, f1.w), pkrtz(f2.w, f3.w), 0, 1, 2, 3);
    }
    __syncthreads();

    const int pix = qu * 1024 + t;
    const int pt  = pix >> 6;
    const int pl  = pix & 63;
    const int4* __restrict__ descb =
        g_desc + (size_t)((b * DG_ + g) * 9) * HW_ + pix;
    uint2* __restrict__ outb =
        g_colq + ((size_t)(b * 64 + pt) * NQP_ + cq) * 64 + pl;

    int4 d[9];
#pragma unroll
    for (int k = 0; k < 9; ++k) d[k] = descb[(size_t)k * HW_];

#pragma unroll
    for (int k = 0; k < 9; ++k) {
        const h2v wl = __builtin_bit_cast(h2v, d[k].y);
        const h2v wh = __builtin_bit_cast(h2v, d[k].z);
        const h4v* p = s_x4 + d[k].x;
        const h4v lo0 = p[0];
        const h4v lo1 = p[1];
        const h4v hi0 = p[XSTR_];
        const h4v hi1 = p[XSTR_ + 1];
        float v[4];
#pragma unroll
        for (int ci = 0; ci < 4; ++ci) {
            float a;                           // v_fma_mix_f32 chains
            a = (float)wl[0] * (float)lo0[ci];
            a = fmaf((float)wl[1], (float)lo1[ci], a);
            a = fmaf((float)wh[0], (float)hi0[ci], a);
            a = fmaf((float)wh[1], (float)hi1[ci], a);
            v[ci] = a;
        }
        // qp = k*32 + cq; element = {pk(v0,v1), pk(v2,v3)}
        outb[(size_t)k * 32 * 64] = make_uint2(pack_bf16x2_hw(v[0], v[1]),
                                               pack_bf16x2_hw(v[2], v[3]));
    }
}

// ---- Kernel 3: GEMM, zero LDS, zero barriers. 256 blocks x 1024 thr. ----
// 16 waves = 4 co-ranges x 4 pixel-subtiles over a 64-pixel slab. Per kt:
// 2 contiguous A b128 (1KB/wave) + 2 B b64 + 2 MFMA. Depth-1 prefetch.
__global__ __launch_bounds__(1024) void gemm_kernel(
    const float* __restrict__ bias, float* __restrict__ out)
{
    const int bid  = blockIdx.x;           // 256 = 4b * 64 pt64
    const int b    = bid >> 6;
    const int pt   = bid & 63;
    const int t    = threadIdx.x;
    const int w    = t >> 6;               // wave 0..15
    const int cw   = w >> 2;               // co-range (32 co)
    const int nt   = w & 3;                // 16-pixel subtile
    const int lane = t & 63;
    const int l15  = lane & 15;
    const int quad = lane >> 4;

    // A: frag (kt, mt=cw*2+mtl) at ((kt*8+mt)*64 + lane)*8
    const unsigned short* __restrict__ ap = g_wA + ((size_t)(cw * 2) * 64 + lane) * 8;
    // B: lane reads qpairs kt*8 + quad*2 + {0,1} at pixel nt*16+l15
    const uint2* __restrict__ bp =
        g_colq + ((size_t)(b * 64 + pt) * NQP_ + quad * 2) * 64 + nt * 16 + l15;

    floatx4 acc0 = {0.f, 0.f, 0.f, 0.f};
    floatx4 acc1 = {0.f, 0.f, 0.f, 0.f};

    short8 a0c = *(const short8*)ap;
    short8 a1c = *(const short8*)(ap + 512);
    uint2 ua = bp[0], ub = bp[64];
    uint4 u0 = make_uint4(ua.x, ua.y, ub.x, ub.y);
    short8 b_c = __builtin_bit_cast(short8, u0);

#pragma unroll 4
    for (int kt = 0; kt < NKT_; ++kt) {
        short8 a0n = a0c, a1n = a1c, b_n = b_c;
        if (kt < NKT_ - 1) {
            const unsigned short* an = ap + (size_t)(kt + 1) * 4096;
            a0n = *(const short8*)an;
            a1n = *(const short8*)(an + 512);
            const uint2* bq = bp + (size_t)(kt + 1) * 512;
            const uint2 va = bq[0], vb = bq[64];
            b_n = __builtin_bit_cast(short8, make_uint4(va.x, va.y, vb.x, vb.y));
        }
        acc0 = __builtin_amdgcn_mfma_f32_16x16x32_bf16(a0c, b_c, acc0, 0, 0, 0);
        acc1 = __builtin_amdgcn_mfma_f32_16x16x32_bf16(a1c, b_c, acc1, 0, 0, 0);
        a0c = a0n; a1c = a1n; b_c = b_n;
    }

    // C/D: col = l15 (pixel), row = quad*4 + r (co within 16-tile)
    const int pixo = pt * 64 + nt * 16 + l15;
#pragma unroll
    for (int mtl = 0; mtl < 2; ++mtl) {
        const floatx4 a = mtl ? acc1 : acc0;
        const int cob = cw * 32 + mtl * 16 + quad * 4;
#pragma unroll
        for (int r = 0; r < 4; ++r) {
            const int co = cob + r;
            out[((size_t)(b * CO_ + co) << 12) + pixo] = a[r] + bias[co];
        }
    }
}

extern "C" void kernel_launch(void* const* d_in, const int* in_sizes, int n_in,
                              void* d_out, int out_size, void* d_ws, size_t ws_size,
                              hipStream_t stream) {
    const float* x      = (const float*)d_in[0];
    const float* offset = (const float*)d_in[1];
    const float* mask   = (const float*)d_in[2];
    const float* weight = (const float*)d_in[3];
    const float* bias   = (const float*)d_in[4];
    float* out = (float*)d_out;

    hipLaunchKernelGGL(prep_kernel, dim3(576 + 1152), dim3(256), 0, stream, weight, offset, mask);
    hipLaunchKernelGGL(col_kernel, dim3(512), dim3(1024), 0, stream, x);
    hipLaunchKernelGGL(gemm_kernel, dim3(256), dim3(1024), 0, stream, bias, out);
}

// Round 12
// 100.711 us; speedup vs baseline: 1.0271x; 1.0271x over previous
//
#include <hip/hip_runtime.h>
#include <hip/hip_fp16.h>
#include <hip/hip_bf16.h>

// Problem constants (fixed by reference setup_inputs)
#define B_    4
#define C_    128
#define H_    64
#define W_    64
#define CO_   128
#define K_    9
#define DG_   2
#define HW_   4096
#define CK_   1152
#define NKT_  36        // CK_/32
#define NQP_  288       // CK_/4 channel-quad "qpairs"
#define XSTR_ 68        // LDS plane row stride in h4v elements (8B): bank-rotating

typedef __attribute__((ext_vector_type(8))) short    short8;
typedef __attribute__((ext_vector_type(4))) float    floatx4;
typedef __attribute__((ext_vector_type(2))) _Float16 h2v;
typedef __attribute__((ext_vector_type(4))) _Float16 h4v;    // 8B, one pixel x 4 channels

__device__ __forceinline__ h2v pkrtz(float a, float b) {
    return __builtin_bit_cast(h2v, __builtin_amdgcn_cvt_pkrtz(a, b));  // v_cvt_pkrtz_f16_f32
}

// Static staging buffers, fully rewritten every launch.
// K-dimension reordered k-major: ck' = k*128 + c (A and B agree; GEMM is
// order-invariant). A in MFMA-fragment order: [kt][mt(co16)][lane][8k'].
__device__ __align__(16) unsigned short g_wA[NKT_ * 8 * 64 * 8];
// col 64-pixel-tile-blocked, quad-packed: [b][pt64][qp(288)][pl64] uint2,
// qp = k*32 + c/4; element = {bf16x2(ck'=4q,4q+1), bf16x2(ck'=4q+2,4q+3)}.
__device__ __align__(16) uint2          g_colq[(size_t)B_ * 64 * NQP_ * 64];
__device__ __align__(16) int4           g_desc[B_ * DG_ * K_ * HW_];   // {padded base, h2(w00,w01), h2(w10,w11), 0}

__device__ __forceinline__ unsigned short f32_to_bf16(float f) {
    unsigned int u = __float_as_uint(f);
    u += 0x7FFFu + ((u >> 16) & 1u);           // round-to-nearest-even
    return (unsigned short)(u >> 16);
}
__device__ __forceinline__ unsigned int pack_bf16x2_hw(float a, float b) {
    union { __hip_bfloat162 h; unsigned int u; } cvt;
    cvt.h = __float22bfloat162_rn(make_float2(a, b));  // v_cvt_pk_bf16_f32
    return cvt.u;
}

// ---- Kernel 1: weight -> bf16 A-fragment layout (k-major) + descriptors ----
__global__ __launch_bounds__(256) void prep_kernel(
    const float* __restrict__ w,
    const float* __restrict__ offset,
    const float* __restrict__ mask)
{
    const int bid = blockIdx.x;
    if (bid < 576) {
        // weights: 147456 elements into fragment order, k-major ck'
        const int lin  = bid * 256 + threadIdx.x;
        const int j    = lin & 7;
        const int lane = (lin >> 3) & 63;
        const int mtkt = lin >> 9;             // kt*8 + mt
        const int mt   = mtkt & 7;
        const int kt   = mtkt >> 3;
        const int co   = mt * 16 + (lane & 15);
        const int kp   = kt * 32 + (lane >> 4) * 8 + j;   // ck' = k*128 + c
        const int c    = kp & 127;
        const int k    = kp >> 7;
        g_wA[lin] = f32_to_bf16(w[co * CK_ + c * 9 + k]);
    } else {
        // descriptors: 294912 = 72 bgk * 4096 pix
        const int lin = (bid - 576) * 256 + threadIdx.x;
        const int pix = lin & (HW_ - 1);
        const int bgk = lin >> 12;             // (b*2+g)*9 + k
        const int k   = bgk % 9;
        const int bg  = bgk / 9;
        const int ho = pix >> 6;
        const int wo = pix & 63;
        const int ky = k / 3;
        const int kx = k - 3 * ky;

        const float py = offset[(size_t)(bg * 18 + 2 * k)     * HW_ + pix] + (float)(ho - 1 + ky);
        const float px = offset[(size_t)(bg * 18 + 2 * k + 1) * HW_ + pix] + (float)(wo - 1 + kx);
        const float m  = mask  [(size_t)(bg * 9 + k)          * HW_ + pix];

        const float y0f = floorf(py);
        const float x0f = floorf(px);
        const float ly = py - y0f;
        const float lx = px - x0f;
        const int y0 = (int)y0f;
        const int x0 = (int)x0f;

        // clamped 2x2 load window + folded edge weights
        const bool yin = (y0 >= 0) & (y0 <= H_ - 2);
        const float er0 = yin ? (1.0f - ly) : ((y0 == -1)     ? ly          : 0.0f);
        const float er1 = yin ? ly          : ((y0 == H_ - 1) ? (1.0f - ly) : 0.0f);
        const bool xin = (x0 >= 0) & (x0 <= W_ - 2);
        const float ec0 = xin ? (1.0f - lx) : ((x0 == -1)     ? lx          : 0.0f);
        const float ec1 = xin ? lx          : ((x0 == W_ - 1) ? (1.0f - lx) : 0.0f);
        const int yc = min(max(y0, 0), H_ - 2);
        const int xc = min(max(x0, 0), W_ - 2);

        const __half2 wlo = __floats2half2_rn(m * er0 * ec0, m * er0 * ec1);
        const __half2 whi = __floats2half2_rn(m * er1 * ec0, m * er1 * ec1);
        union { __half2 h; int i; } ulo, uhi;
        ulo.h = wlo; uhi.h = whi;
        int4 d;
        d.x = yc * XSTR_ + xc;                 // padded-plane ELEMENT base
        d.y = ulo.i;
        d.z = uhi.i;
        d.w = 0;
        g_desc[lin] = d;
    }
}

// ---- Kernel 2 (hot): col from 4-channel-interleaved fp16 LDS planes. ----
// Block = (b, channel-quad, pixel-quarter): 512 blocks x 1024 thr (2/CU).
// Tap-row read = ds_read2_b64; bilinear via v_fma_mix_f32 (f16 srcs, f32 acc);
// per-k one uint2 store (512B/wave, contiguous).
__global__ __launch_bounds__(1024) void col_kernel(const float* __restrict__ x)
{
    const int bid = blockIdx.x;            // 512 = 4b * 32cq * 4qu
    const int b   = bid >> 7;
    const int rem = bid & 127;
    const int cq  = rem >> 2;              // channel quad 0..31
    const int qu  = rem & 3;
    const int c0  = cq * 4;
    const int g   = cq >> 4;               // deform group
    const int t   = threadIdx.x;

    __shared__ h4v s_x4[64 * XSTR_];       // 34816 B

    {   // stage 4 planes interleaved: thread t -> pixels 4t..4t+3
        const int p0  = t * 4;
        const int row = p0 >> 6;
        const int col = p0 & 63;
        const float* __restrict__ src = x + ((size_t)(b * C_ + c0) << 12) + p0;
        const float4 f0 = *(const float4*)(src);
        const float4 f1 = *(const float4*)(src + HW_);
        const float4 f2 = *(const float4*)(src + 2 * HW_);
        const float4 f3 = *(const float4*)(src + 3 * HW_);
        h4v* dst = s_x4 + row * XSTR_ + col;
        dst[0] = __builtin_shufflevector(pkrtz(f0.x, f1.x), pkrtz(f2.x, f3.x), 0, 1, 2, 3);
        dst[1] = __builtin_shufflevector(pkrtz(f0.y, f1.y), pkrtz(f2.y, f3.y), 0, 1, 2, 3);
        dst[2] = __builtin_shufflevector(pkrtz(f0.z, f1.z), pkrtz(f2.z, f3.z), 0, 1, 2, 3);
        dst[3] = __builtin_shufflevector(pkrtz(f0.w, f1.w), pkrtz(f2.w, f3.w), 0, 1, 2, 3);
    }
    __syncthreads();

    const int pix = qu * 1024 + t;
    const int pt  = pix >> 6;
    const int pl  = pix & 63;
    const int4* __restrict__ descb =
        g_desc + (size_t)((b * DG_ + g) * 9) * HW_ + pix;
    uint2* __restrict__ outb =
        g_colq + ((size_t)(b * 64 + pt) * NQP_ + cq) * 64 + pl;

    int4 d[9];
#pragma unroll
    for (int k = 0; k < 9; ++k) d[k] = descb[(size_t)k * HW_];

#pragma unroll
    for (int k = 0; k < 9; ++k) {
        const h2v wl = __builtin_bit_cast(h2v, d[k].y);
        const h2v wh = __builtin_bit_cast(h2v, d[k].z);
        const h4v* p = s_x4 + d[k].x;
        const h4v lo0 = p[0];
        const h4v lo1 = p[1];
        const h4v hi0 = p[XSTR_];
        const h4v hi1 = p[XSTR_ + 1];
        float v[4];
#pragma unroll
        for (int ci = 0; ci < 4; ++ci) {
            float a;                           // v_fma_mix_f32 chains
            a = (float)wl[0] * (float)lo0[ci];
            a = fmaf((float)wl[1], (float)lo1[ci], a);
            a = fmaf((float)wh[0], (float)hi0[ci], a);
            a = fmaf((float)wh[1], (float)hi1[ci], a);
            v[ci] = a;
        }
        // qp = k*32 + cq; element = {pk(v0,v1), pk(v2,v3)}
        outb[(size_t)k * 32 * 64] = make_uint2(pack_bf16x2_hw(v[0], v[1]),
                                               pack_bf16x2_hw(v[2], v[3]));
    }
}

// ---- Kernel 3: GEMM with register-level A-reuse. 256 blocks x 512 thr. ----
// 8 waves = 4 co-ranges x 2 nt-groups; each wave loads its 2 A-frags ONCE
// per kt and feeds 2 B-frags (2 nt) -> 4 MFMA. A L2 traffic halves vs R11
// (295 -> 147 MB). Zero LDS, zero barriers, depth-1 prefetch.
__global__ __launch_bounds__(512) void gemm_kernel(
    const float* __restrict__ bias, float* __restrict__ out)
{
    const int bid  = blockIdx.x;           // 256 = 4b * 64 pt64
    const int b    = bid >> 6;
    const int pt   = bid & 63;
    const int t    = threadIdx.x;
    const int w    = t >> 6;               // wave 0..7
    const int cw   = w & 3;                // co-range (32 co)
    const int ntg  = w >> 2;               // nt-group: pixels ntg*32..+32
    const int lane = t & 63;
    const int l15  = lane & 15;
    const int quad = lane >> 4;

    // A: frag (kt, mt=cw*2+mtl) at ((kt*8+mt)*64 + lane)*8
    const unsigned short* __restrict__ ap = g_wA + ((size_t)(cw * 2) * 64 + lane) * 8;
    // B: lane reads qpairs kt*8 + quad*2 + {0,1} at pixel ntg*32 + i*16 + l15
    const uint2* __restrict__ bp =
        g_colq + ((size_t)(b * 64 + pt) * NQP_ + quad * 2) * 64 + ntg * 32 + l15;

    floatx4 acc[2][2];
#pragma unroll
    for (int m = 0; m < 2; ++m)
#pragma unroll
        for (int i = 0; i < 2; ++i) acc[m][i] = floatx4{0.f, 0.f, 0.f, 0.f};

    short8 a0c = *(const short8*)ap;
    short8 a1c = *(const short8*)(ap + 512);
    short8 bc[2];
#pragma unroll
    for (int i = 0; i < 2; ++i) {
        const uint2 va = bp[i * 16], vb = bp[i * 16 + 64];
        bc[i] = __builtin_bit_cast(short8, make_uint4(va.x, va.y, vb.x, vb.y));
    }

#pragma unroll 2
    for (int kt = 0; kt < NKT_; ++kt) {
        short8 a0n = a0c, a1n = a1c, bn[2] = { bc[0], bc[1] };
        if (kt < NKT_ - 1) {
            const unsigned short* an = ap + (size_t)(kt + 1) * 4096;
            a0n = *(const short8*)an;
            a1n = *(const short8*)(an + 512);
            const uint2* bq = bp + (size_t)(kt + 1) * 512;
#pragma unroll
            for (int i = 0; i < 2; ++i) {
                const uint2 va = bq[i * 16], vb = bq[i * 16 + 64];
                bn[i] = __builtin_bit_cast(short8, make_uint4(va.x, va.y, vb.x, vb.y));
            }
        }
#pragma unroll
        for (int i = 0; i < 2; ++i) {
            acc[0][i] = __builtin_amdgcn_mfma_f32_16x16x32_bf16(a0c, bc[i], acc[0][i], 0, 0, 0);
            acc[1][i] = __builtin_amdgcn_mfma_f32_16x16x32_bf16(a1c, bc[i], acc[1][i], 0, 0, 0);
        }
        a0c = a0n; a1c = a1n; bc[0] = bn[0]; bc[1] = bn[1];
    }

    // C/D: col = l15 (pixel), row = quad*4 + r (co within 16-tile)
#pragma unroll
    for (int mtl = 0; mtl < 2; ++mtl) {
        const int cob = cw * 32 + mtl * 16 + quad * 4;
#pragma unroll
        for (int i = 0; i < 2; ++i) {
            const int pixo = pt * 64 + ntg * 32 + i * 16 + l15;
#pragma unroll
            for (int r = 0; r < 4; ++r) {
                const int co = cob + r;
                out[((size_t)(b * CO_ + co) << 12) + pixo] = acc[mtl][i][r] + bias[co];
            }
        }
    }
}

extern "C" void kernel_launch(void* const* d_in, const int* in_sizes, int n_in,
                              void* d_out, int out_size, void* d_ws, size_t ws_size,
                              hipStream_t stream) {
    const float* x      = (const float*)d_in[0];
    const float* offset = (const float*)d_in[1];
    const float* mask   = (const float*)d_in[2];
    const float* weight = (const float*)d_in[3];
    const float* bias   = (const float*)d_in[4];
    float* out = (float*)d_out;

    hipLaunchKernelGGL(prep_kernel, dim3(576 + 1152), dim3(256), 0, stream, weight, offset, mask);
    hipLaunchKernelGGL(col_kernel, dim3(512), dim3(1024), 0, stream, x);
    hipLaunchKernelGGL(gemm_kernel, dim3(256), dim3(512), 0, stream, bias, out);
}